// Round 3
// baseline (1125.912 us; speedup 1.0000x reference)
//
#include <hip/hip_runtime.h>

#define NB 16
#define NC 64
#define C2 32
#define C4 16
#define HH 256
#define WW 256
#define HW (HH*WW)          // 65536

// ws layout (floats):
//   [0, 2048)        w1T   : w1T[c*32+o] = w1[o*64+c]
//   [2048, 10240)    S1    : [b][o32][s16]   (per-b stride 512)
//   [10240, 18432)   S2
//   [18432, 26624)   S3
//   [26624, 30720)   gates : [b][o16][s16]   (per-b stride 256)

__global__ __launch_bounds__(256) void prep_kernel(const float* __restrict__ w1,
                                                   float* __restrict__ ws) {
    int t = threadIdx.x;
    for (int i = t; i < 24576; i += 256) ws[2048 + i] = 0.f;
    for (int i = t; i < 2048; i += 256) {
        int o = i >> 6, c = i & 63;
        ws[c * 32 + o] = w1[i];
    }
}

// Stats: S1,S2,S3 per (b, o in [0,32), s in [0,16)) over the 4096 spatial blocks.
// One pixel per thread; all 64 channel loads issued up-front (out_kernel-proven
// MLP structure); butterfly-reduce over the 16 lanes sharing w%4; LDS combine
// across the 4 waves; one atomicAdd per (o,s,stat) per block.
__global__ __launch_bounds__(256) void stats_kernel(const float* __restrict__ x,
                                                    const float* __restrict__ w1t,
                                                    const float* __restrict__ b1,
                                                    float* __restrict__ stats) {
    int b    = blockIdx.x >> 8;    // 256 row-blocks per batch
    int h    = blockIdx.x & 255;
    int t    = threadIdx.x;        // w = t
    int lane = t & 63;
    int wid  = t >> 6;
    const float* xp = x + (size_t)b * NC * HW + (size_t)h * WW + t;

    float xr[64];
    #pragma unroll
    for (int c = 0; c < 64; c++) xr[c] = xp[(size_t)c * HW];

    float acc[32];
    #pragma unroll
    for (int o = 0; o < 32; o++) acc[o] = b1[o];
    #pragma unroll
    for (int c = 0; c < 64; c++) {
        float xc = xr[c];
        #pragma unroll
        for (int o = 0; o < 32; o++) acc[o] += w1t[c * 32 + o] * xc;
    }

    __shared__ float red[3][4][128];
    #pragma unroll
    for (int o = 0; o < 32; o++) {
        float v = fmaxf(acc[o], 0.f);
        float p = v * v;
        float q = p * v;
        #pragma unroll
        for (int m = 4; m <= 32; m <<= 1) {
            v += __shfl_xor(v, m);
            p += __shfl_xor(p, m);
            q += __shfl_xor(q, m);
        }
        if (lane < 4) {                       // lane&3 == lane -> s4 = lane
            red[0][wid][o * 4 + lane] = v;
            red[1][wid][o * 4 + lane] = p;
            red[2][wid][o * 4 + lane] = q;
        }
    }
    __syncthreads();
    if (t < 128) {
        int o = t >> 2, s4 = t & 3;
        int idx = b * 512 + o * 16 + (h & 3) * 4 + s4;
        #pragma unroll
        for (int st = 0; st < 3; st++) {
            float v = red[st][0][t] + red[st][1][t] + red[st][2][t] + red[st][3][t];
            atomicAdd(&stats[st * 8192 + idx], v);
        }
    }
}

// Tiny attention: qkv = mean + m3; softmax(q q^T) @ v; gate = sigmoid(y).
__global__ __launch_bounds__(512) void attn_kernel(const float* __restrict__ stats,
                                                   float* __restrict__ gates) {
    int b = blockIdx.x;
    int t = threadIdx.x;
    __shared__ float qkv[512];
    {
        int idx = b * 512 + t;
        float S1 = stats[idx];
        float S2 = stats[8192 + idx];
        float S3 = stats[16384 + idx];
        float mu = S1 * (1.f / 4096.f);
        float m3 = (S3 - 3.f * mu * S2 + 2.f * 4096.f * mu * mu * mu) * (1.f / 16.f);
        qkv[t] = mu + m3;
    }
    __syncthreads();
    if (t < 256) {
        int o = t >> 4, s = t & 15;
        float qs = qkv[o * 16 + s];
        float mx = -1e30f;
        #pragma unroll
        for (int k = 0; k < 16; k++) mx = fmaxf(mx, qs * qkv[o * 16 + k]);
        float sum = 0.f, y = 0.f;
        #pragma unroll
        for (int k = 0; k < 16; k++) {
            float e = __expf(qs * qkv[o * 16 + k] - mx);
            sum += e;
            y   += e * qkv[(16 + o) * 16 + k];
        }
        y /= sum;
        float g = 1.f / (1.f + __expf(-y));
        gates[b * 256 + o * 16 + s] = g;
    }
}

// Per-pixel: recompute vx channels, gate, 16->64 conv, + bias + residual.
__global__ __launch_bounds__(256) void out_kernel(const float* __restrict__ x,
                                                  const float* __restrict__ w1t,
                                                  const float* __restrict__ b1,
                                                  const float* __restrict__ w2,
                                                  const float* __restrict__ b2,
                                                  const float* __restrict__ gates,
                                                  float* __restrict__ out) {
    int bh = blockIdx.x;
    int b  = bh >> 8;      // 256 rows per batch
    int h  = bh & 255;
    int w  = threadIdx.x;  // 0..255
    int s  = (h & 3) * 4 + (w & 3);
    const float* xb = x   + (size_t)b * NC * HW + h * WW + w;
    float*       ob = out + (size_t)b * NC * HW + h * WW + w;

    __shared__ float gsh[256];
    gsh[w] = gates[b * 256 + w];
    __syncthreads();

    float xr[64];
    #pragma unroll
    for (int c = 0; c < 64; c++) xr[c] = xb[(size_t)c * HW];

    float fv[16];
    #pragma unroll
    for (int j = 0; j < 16; j++) fv[j] = b1[16 + j];
    #pragma unroll
    for (int c = 0; c < 64; c++) {
        float xc = xr[c];
        #pragma unroll
        for (int j = 0; j < 16; j++) fv[j] += w1t[c * 32 + 16 + j] * xc;
    }
    #pragma unroll
    for (int j = 0; j < 16; j++) {
        float v = fv[j] > 0.f ? fv[j] : 0.f;
        fv[j] = v * gsh[j * 16 + s];
    }
    #pragma unroll
    for (int o = 0; o < 64; o++) {
        float r = b2[o] + xr[o];
        #pragma unroll
        for (int j = 0; j < 16; j++) r += w2[o * 16 + j] * fv[j];
        ob[(size_t)o * HW] = r;
    }
}

extern "C" void kernel_launch(void* const* d_in, const int* in_sizes, int n_in,
                              void* d_out, int out_size, void* d_ws, size_t ws_size,
                              hipStream_t stream) {
    const float* x  = (const float*)d_in[0];
    const float* w1 = (const float*)d_in[1];
    const float* b1 = (const float*)d_in[2];
    const float* w2 = (const float*)d_in[3];
    const float* b2 = (const float*)d_in[4];
    float* ws    = (float*)d_ws;
    float* w1t   = ws;
    float* stats = ws + 2048;
    float* gates = ws + 26624;
    float* out   = (float*)d_out;

    prep_kernel <<<1,    256, 0, stream>>>(w1, ws);
    stats_kernel<<<4096, 256, 0, stream>>>(x, w1t, b1, stats);
    attn_kernel <<<16,   512, 0, stream>>>(stats, gates);
    out_kernel  <<<4096, 256, 0, stream>>>(x, w1t, b1, w2, b2, gates, out);
}

// Round 4
// 350.530 us; speedup vs baseline: 3.2120x; 3.2120x over previous
//
#include <hip/hip_runtime.h>

#define NB 16
#define NC 64
#define C2 32
#define C4 16
#define HH 256
#define WW 256
#define HW (HH*WW)          // 65536

// ws layout (floats):
//   [0, 2048)        w1T   : w1T[c*32+o] = w1[o*64+c]
//   [2048, 10240)    S1    : [b][o32][s16]   (per-b stride 512)
//   [10240, 18432)   S2
//   [18432, 26624)   S3
//   [26624, 30720)   gates : [b][o16][s16]   (per-b stride 256)

__global__ __launch_bounds__(256) void prep_kernel(const float* __restrict__ w1,
                                                   float* __restrict__ ws) {
    int t = threadIdx.x;
    for (int i = t; i < 24576; i += 256) ws[2048 + i] = 0.f;
    for (int i = t; i < 2048; i += 256) {
        int o = i >> 6, c = i & 63;
        ws[c * 32 + o] = w1[i];
    }
}

// Stats: S1,S2,S3 per (b, o in [0,32), s in [0,16)) over the 4096 spatial blocks.
// Block = (b, r=h%4, chunk). Thread = column; owns 8 rows (all h%4==r -> fixed s).
// Per pixel: 64 loads issued up-front (pinned by sched_barrier), 64x32 conv,
// moment accumulation in registers. One butterfly reduction + atomics per thread.
__global__ __launch_bounds__(256, 2) void stats_kernel(const float* __restrict__ x,
                                                       const float* __restrict__ w1t,
                                                       const float* __restrict__ b1,
                                                       float* __restrict__ stats) {
    int b     = blockIdx.x >> 5;   // 32 blocks per batch
    int sub   = blockIdx.x & 31;
    int r     = sub >> 3;          // h residue 0..3
    int chunk = sub & 7;           // 8 row-chunks
    int t     = threadIdx.x;       // column w
    int lane  = t & 63;
    int wid   = t >> 6;
    const float* xb = x + (size_t)b * NC * HW + t;

    float S1[32], S2[32], S3[32];
    #pragma unroll
    for (int o = 0; o < 32; o++) { S1[o] = 0.f; S2[o] = 0.f; S3[o] = 0.f; }

    #pragma unroll 1
    for (int p = 0; p < 8; ++p) {
        int h = r + 4 * (chunk * 8 + p);
        const float* xp = xb + (size_t)h * WW;

        float xr[64];
        #pragma unroll
        for (int c = 0; c < 64; c++) xr[c] = xp[(size_t)c * HW];
        __builtin_amdgcn_sched_barrier(0);   // keep all 64 loads ahead of the conv

        float acc[32];
        #pragma unroll
        for (int o = 0; o < 32; o++) acc[o] = b1[o];
        #pragma unroll
        for (int c = 0; c < 64; c++) {
            float xc = xr[c];
            #pragma unroll
            for (int o = 0; o < 32; o++) acc[o] += w1t[c * 32 + o] * xc;
        }
        #pragma unroll
        for (int o = 0; o < 32; o++) {
            float v = fmaxf(acc[o], 0.f);
            float pw = v * v;
            S1[o] += v;
            S2[o] += pw;
            S3[o] += pw * v;
        }
    }

    // Butterfly-reduce over the 16 lanes sharing (lane & 3), then combine the
    // 4 waves through LDS; one atomicAdd per (o, s4, stat) per block.
    __shared__ float red[3][4][128];
    #pragma unroll
    for (int o = 0; o < 32; o++) {
        float a = S1[o], bb = S2[o], cc = S3[o];
        #pragma unroll
        for (int m = 4; m <= 32; m <<= 1) {
            a  += __shfl_xor(a,  m);
            bb += __shfl_xor(bb, m);
            cc += __shfl_xor(cc, m);
        }
        if (lane < 4) {
            red[0][wid][o * 4 + lane] = a;
            red[1][wid][o * 4 + lane] = bb;
            red[2][wid][o * 4 + lane] = cc;
        }
    }
    __syncthreads();
    if (t < 128) {
        int o = t >> 2, s4 = t & 3;
        int idx = b * 512 + o * 16 + r * 4 + s4;
        #pragma unroll
        for (int st = 0; st < 3; st++) {
            float v = red[st][0][t] + red[st][1][t] + red[st][2][t] + red[st][3][t];
            atomicAdd(&stats[st * 8192 + idx], v);
        }
    }
}

// Tiny attention: qkv = mean + m3; softmax(q q^T) @ v; gate = sigmoid(y).
__global__ __launch_bounds__(512) void attn_kernel(const float* __restrict__ stats,
                                                   float* __restrict__ gates) {
    int b = blockIdx.x;
    int t = threadIdx.x;
    __shared__ float qkv[512];
    {
        int idx = b * 512 + t;
        float S1 = stats[idx];
        float S2 = stats[8192 + idx];
        float S3 = stats[16384 + idx];
        float mu = S1 * (1.f / 4096.f);
        float m3 = (S3 - 3.f * mu * S2 + 2.f * 4096.f * mu * mu * mu) * (1.f / 16.f);
        qkv[t] = mu + m3;
    }
    __syncthreads();
    if (t < 256) {
        int o = t >> 4, s = t & 15;
        float qs = qkv[o * 16 + s];
        float mx = -1e30f;
        #pragma unroll
        for (int k = 0; k < 16; k++) mx = fmaxf(mx, qs * qkv[o * 16 + k]);
        float sum = 0.f, y = 0.f;
        #pragma unroll
        for (int k = 0; k < 16; k++) {
            float e = __expf(qs * qkv[o * 16 + k] - mx);
            sum += e;
            y   += e * qkv[(16 + o) * 16 + k];
        }
        y /= sum;
        float g = 1.f / (1.f + __expf(-y));
        gates[b * 256 + o * 16 + s] = g;
    }
}

// Per-pixel: recompute vx channels, gate, 16->64 conv, + bias + residual.
__global__ __launch_bounds__(256) void out_kernel(const float* __restrict__ x,
                                                  const float* __restrict__ w1t,
                                                  const float* __restrict__ b1,
                                                  const float* __restrict__ w2,
                                                  const float* __restrict__ b2,
                                                  const float* __restrict__ gates,
                                                  float* __restrict__ out) {
    int bh = blockIdx.x;
    int b  = bh >> 8;      // 256 rows per batch
    int h  = bh & 255;
    int w  = threadIdx.x;  // 0..255
    int s  = (h & 3) * 4 + (w & 3);
    const float* xb = x   + (size_t)b * NC * HW + h * WW + w;
    float*       ob = out + (size_t)b * NC * HW + h * WW + w;

    __shared__ float gsh[256];
    gsh[w] = gates[b * 256 + w];
    __syncthreads();

    float xr[64];
    #pragma unroll
    for (int c = 0; c < 64; c++) xr[c] = xb[(size_t)c * HW];

    float fv[16];
    #pragma unroll
    for (int j = 0; j < 16; j++) fv[j] = b1[16 + j];
    #pragma unroll
    for (int c = 0; c < 64; c++) {
        float xc = xr[c];
        #pragma unroll
        for (int j = 0; j < 16; j++) fv[j] += w1t[c * 32 + 16 + j] * xc;
    }
    #pragma unroll
    for (int j = 0; j < 16; j++) {
        float v = fv[j] > 0.f ? fv[j] : 0.f;
        fv[j] = v * gsh[j * 16 + s];
    }
    #pragma unroll
    for (int o = 0; o < 64; o++) {
        float r = b2[o] + xr[o];
        #pragma unroll
        for (int j = 0; j < 16; j++) r += w2[o * 16 + j] * fv[j];
        ob[(size_t)o * HW] = r;
    }
}

extern "C" void kernel_launch(void* const* d_in, const int* in_sizes, int n_in,
                              void* d_out, int out_size, void* d_ws, size_t ws_size,
                              hipStream_t stream) {
    const float* x  = (const float*)d_in[0];
    const float* w1 = (const float*)d_in[1];
    const float* b1 = (const float*)d_in[2];
    const float* w2 = (const float*)d_in[3];
    const float* b2 = (const float*)d_in[4];
    float* ws    = (float*)d_ws;
    float* w1t   = ws;
    float* stats = ws + 2048;
    float* gates = ws + 26624;
    float* out   = (float*)d_out;

    prep_kernel <<<1,   256, 0, stream>>>(w1, ws);
    stats_kernel<<<512, 256, 0, stream>>>(x, w1t, b1, stats);
    attn_kernel <<<16,  512, 0, stream>>>(stats, gates);
    out_kernel  <<<4096, 256, 0, stream>>>(x, w1t, b1, w2, b2, gates, out);
}